// Round 5
// baseline (650.722 us; speedup 1.0000x reference)
//
#include <hip/hip_runtime.h>
#include <cstdint>

typedef unsigned short u16;
typedef unsigned int u32;

typedef _Float16 f16x8 __attribute__((ext_vector_type(8)));
typedef float f32x4 __attribute__((ext_vector_type(4)));

static constexpr int Bb = 2, Ss = 4096, Dd = 1024, Ff = 4096;
static constexpr int Mtok = Bb * Ss;          // 8192
static constexpr int NCH = 128;               // scan chunks per sequence
static constexpr int TCH = Ss / NCH;          // 32 steps per chunk

__device__ __forceinline__ float h2f(u16 u) {
    union { u16 u; _Float16 h; } w; w.u = u; return (float)w.h;
}
__device__ __forceinline__ u16 f2h(float f) {
    union { _Float16 h; u16 u; } w; w.h = (_Float16)f; return w.u;
}

// ---------------- convert fp32 -> fp16, vectorized ----------------
__global__ __launch_bounds__(256) void cvt_f32_f16(const float* __restrict__ src,
                                                   u16* __restrict__ dst) {
    const long i = ((long)blockIdx.x * 256 + threadIdx.x) * 4;
    float4 f = *(const float4*)(src + i);
    ushort4 o;
    o.x = f2h(f.x); o.y = f2h(f.y); o.z = f2h(f.z); o.w = f2h(f.w);
    *(ushort4*)(dst + i) = o;
}

// ---------- transpose+convert: src fp32 [K,N] row-major -> dst fp16 [N,K] ----------
__global__ __launch_bounds__(1024) void transpose_f32_f16(const float* __restrict__ src,
                                                          u16* __restrict__ dst,
                                                          int K, int N) {
    __shared__ u16 t[32][33];
    const int tx = threadIdx.x, ty = threadIdx.y;
    const int n0 = blockIdx.x * 32, k0 = blockIdx.y * 32;
    t[ty][tx] = f2h(src[(long)(k0 + ty) * N + n0 + tx]);
    __syncthreads();
    dst[(long)(n0 + ty) * K + k0 + tx] = t[tx][ty];
}

// ---------------- GEMM: C[M,N] = A[M,K] @ B[K,N], BT given as [N,K], all fp16 ----------------
// EPI: 0 = none, 1 = +bias, gelu(tanh), 2 = +bias   (bias is fp32)
template <int EPI>
__global__ __launch_bounds__(256, 2) void gemm_bt(const u16* __restrict__ A,
                                                  const u16* __restrict__ BT,
                                                  u16* __restrict__ C,
                                                  const float* __restrict__ bias,
                                                  int M, int N, int K) {
    __shared__ __align__(16) u16 sA[128 * 32];
    __shared__ __align__(16) u16 sB[128 * 32];
    const int tid = threadIdx.x;
    const int tm = blockIdx.y * 128;
    const int tn = blockIdx.x * 128;
    const int w = tid >> 6;
    const int lane = tid & 63;
    const int wm = (w >> 1) * 64;
    const int wn = (w & 1) * 64;
    const int q = lane >> 4;
    const int r16 = lane & 15;

    f32x4 acc[4][4];
#pragma unroll
    for (int i = 0; i < 4; i++)
#pragma unroll
        for (int j = 0; j < 4; j++) acc[i][j] = (f32x4){0.f, 0.f, 0.f, 0.f};

    const int s0 = tid, s1 = 256 + tid;
    const int row0 = s0 >> 2, kc0 = (s0 & 3) * 8;
    const int row1 = s1 >> 2, kc1 = (s1 & 3) * 8;
    const u16* Ar0 = A + (long)(tm + row0) * K + kc0;
    const u16* Ar1 = A + (long)(tm + row1) * K + kc1;
    const u16* Br0 = BT + (long)(tn + row0) * K + kc0;
    const u16* Br1 = BT + (long)(tn + row1) * K + kc1;

    const int kiters = K >> 5;
    for (int kt = 0; kt < kiters; ++kt) {
        const int ko = kt * 32;
        uint4 a0 = *(const uint4*)(Ar0 + ko);
        uint4 a1 = *(const uint4*)(Ar1 + ko);
        uint4 b0 = *(const uint4*)(Br0 + ko);
        uint4 b1 = *(const uint4*)(Br1 + ko);
        *(uint4*)(sA + s0 * 8) = a0;
        *(uint4*)(sA + s1 * 8) = a1;
        *(uint4*)(sB + s0 * 8) = b0;
        *(uint4*)(sB + s1 * 8) = b1;
        __syncthreads();
        f16x8 af[4], bfr[4];
#pragma unroll
        for (int mi = 0; mi < 4; mi++)
            af[mi] = *(const f16x8*)(sA + (wm + mi * 16 + r16) * 32 + q * 8);
#pragma unroll
        for (int ni = 0; ni < 4; ni++)
            bfr[ni] = *(const f16x8*)(sB + (wn + ni * 16 + r16) * 32 + q * 8);
#pragma unroll
        for (int mi = 0; mi < 4; mi++)
#pragma unroll
            for (int ni = 0; ni < 4; ni++)
                acc[mi][ni] = __builtin_amdgcn_mfma_f32_16x16x32_f16(
                    af[mi], bfr[ni], acc[mi][ni], 0, 0, 0);
        __syncthreads();
    }

#pragma unroll
    for (int mi = 0; mi < 4; mi++) {
#pragma unroll
        for (int ni = 0; ni < 4; ni++) {
            const int gcol = tn + wn + ni * 16 + r16;
            float bv = 0.f;
            if (EPI) bv = bias[gcol];
#pragma unroll
            for (int j = 0; j < 4; j++) {
                const int grow = tm + wm + mi * 16 + q * 4 + j;
                float v = acc[mi][ni][j];
                if (EPI) v += bv;
                if (EPI == 1) {
                    float t = tanhf(0.7978845608028654f * (v + 0.044715f * v * v * v));
                    v = 0.5f * v * (1.0f + t);
                }
                C[(long)grow * N + gcol] = f2h(v);
            }
        }
    }
}

// ---------------- a_c transform helper ----------------
__device__ __forceinline__ void a_transform(float ar, float ai, float& cr, float& ci) {
    float m = sqrtf(ar * ar + ai * ai);
    float sg = 1.f / (1.f + __expf(-m));
    float sc = sg / fmaxf(m, 1e-30f);
    cr = ar * sc;
    ci = ai * sc;
}

// ---------------- scan phase 1: per-chunk reduce ----------------
__global__ __launch_bounds__(1024) void scan1(const u16* __restrict__ araw,
                                              const u16* __restrict__ kx,
                                              const u16* __restrict__ vx,
                                              float4* __restrict__ sum4) {
    const int b = blockIdx.y, c = blockIdx.x, d = threadIdx.x;
    float Arp = 1.f, Aip = 0.f, Xr = 0.f, Xi = 0.f;
    const long rowbase = (long)b * Ss + (long)c * TCH;
#pragma unroll 4
    for (int s = 0; s < TCH; ++s) {
        const long row = rowbase + s;
        float ar = h2f(araw[row * 2048 + d]);
        float ai = h2f(araw[row * 2048 + 1024 + d]);
        float kk = h2f(kx[row * 1024 + d]);
        float vv = h2f(vx[row * 1024 + d]);
        float cr, ci;
        a_transform(ar, ai, cr, ci);
        float kv = kk * vv;
        float nXr = cr * Xr - ci * Xi + kv;
        float nXi = cr * Xi + ci * Xr;
        Xr = nXr; Xi = nXi;
        float nAr = cr * Arp - ci * Aip;
        float nAi = cr * Aip + ci * Arp;
        Arp = nAr; Aip = nAi;
    }
    sum4[((long)b * NCH + c) * 1024 + d] = make_float4(Arp, Aip, Xr, Xi);
}

// ---------------- scan phase 2: sequential carry across chunks ----------------
__global__ __launch_bounds__(256) void scan2(const float4* __restrict__ sum4,
                                             float2* __restrict__ carry) {
    const int idx = blockIdx.x * 256 + threadIdx.x;  // 0..2047
    const int b = idx >> 10, d = idx & 1023;
    float hr = 0.f, hi = 0.f;
    for (int cb = 0; cb < NCH / 8; ++cb) {
        float4 t[8];
#pragma unroll
        for (int j = 0; j < 8; j++)
            t[j] = sum4[((long)b * NCH + cb * 8 + j) * 1024 + d];
#pragma unroll
        for (int j = 0; j < 8; j++) {
            carry[((long)b * NCH + cb * 8 + j) * 1024 + d] = make_float2(hr, hi);
            float nr = t[j].x * hr - t[j].y * hi + t[j].z;
            float ni = t[j].x * hi + t[j].y * hr + t[j].w;
            hr = nr; hi = ni;
        }
    }
}

// ---------------- scan phase 3: re-scan with carry, fused silu/q gating ----------------
// qx and yr ALIAS (in-place over q): same-element read-then-write per thread.
__global__ __launch_bounds__(1024) void scan3(const u16* __restrict__ araw,
                                              const u16* __restrict__ kx,
                                              const u16* __restrict__ vx,
                                              const u16* qx,
                                              const u16* __restrict__ gx,
                                              const float2* __restrict__ carry,
                                              u16* yr) {
    const int b = blockIdx.y, c = blockIdx.x, d = threadIdx.x;
    float2 h0 = carry[((long)b * NCH + c) * 1024 + d];
    float hr = h0.x, hi = h0.y;
    const long rowbase = (long)b * Ss + (long)c * TCH;
#pragma unroll 4
    for (int s = 0; s < TCH; ++s) {
        const long row = rowbase + s;
        float ar = h2f(araw[row * 2048 + d]);
        float ai = h2f(araw[row * 2048 + 1024 + d]);
        float kk = h2f(kx[row * 1024 + d]);
        float vv = h2f(vx[row * 1024 + d]);
        float cr, ci;
        a_transform(ar, ai, cr, ci);
        float kv = kk * vv;
        float nhr = cr * hr - ci * hi + kv;
        float nhi = cr * hi + ci * hr;
        hr = nhr; hi = nhi;
        float gg = h2f(gx[row * 1024 + d]);
        float si = gg / (1.f + __expf(-gg));
        float yv = h2f(qx[row * 1024 + d]) * hr * si;
        yr[row * 1024 + d] = f2h(yv);
    }
}

// ---------------- layernorm: out = LN(a + b) * scale + bias ----------------
// a: fp16. RESF32: residual fp32 (else fp16). OUTF32: out fp32 (else fp16).
template <int RESF32, int OUTF32>
__global__ __launch_bounds__(256) void ln_kernel(const u16* __restrict__ a,
                                                 const void* __restrict__ bres,
                                                 const float* __restrict__ scale,
                                                 const float* __restrict__ bias,
                                                 void* __restrict__ out) {
    const int row = blockIdx.x;
    const int tid = threadIdx.x;
    const long base = (long)row * 1024;
    float v[4];
#pragma unroll
    for (int j = 0; j < 4; j++) {
        int d = tid * 4 + j;
        float rb = RESF32 ? ((const float*)bres)[base + d]
                          : h2f(((const u16*)bres)[base + d]);
        v[j] = h2f(a[base + d]) + rb;
    }
    float s = v[0] + v[1] + v[2] + v[3];
    float s2 = v[0] * v[0] + v[1] * v[1] + v[2] * v[2] + v[3] * v[3];
#pragma unroll
    for (int off = 32; off; off >>= 1) {
        s += __shfl_down(s, off);
        s2 += __shfl_down(s2, off);
    }
    __shared__ float red[8];
    const int w = tid >> 6, lane = tid & 63;
    if (lane == 0) { red[w] = s; red[4 + w] = s2; }
    __syncthreads();
    if (tid == 0) {
        float ts = red[0] + red[1] + red[2] + red[3];
        float ts2 = red[4] + red[5] + red[6] + red[7];
        float mu = ts * (1.f / 1024.f);
        float var = ts2 * (1.f / 1024.f) - mu * mu;
        red[0] = mu;
        red[1] = rsqrtf(var + 1e-6f);
    }
    __syncthreads();
    const float mu = red[0], rs = red[1];
#pragma unroll
    for (int j = 0; j < 4; j++) {
        int d = tid * 4 + j;
        float y = (v[j] - mu) * rs * scale[d] + bias[d];
        if (OUTF32) ((float*)out)[base + d] = y;
        else        ((u16*)out)[base + d] = f2h(y);
    }
}

extern "C" void kernel_launch(void* const* d_in, const int* in_sizes, int n_in,
                              void* d_out, int out_size, void* d_ws, size_t ws_size,
                              hipStream_t stream) {
    const float* x    = (const float*)d_in[0];
    const float* Wq   = (const float*)d_in[1];
    const float* Wk   = (const float*)d_in[2];
    const float* Wv   = (const float*)d_in[3];
    const float* Wa   = (const float*)d_in[4];
    const float* Wg   = (const float*)d_in[5];
    const float* Wo   = (const float*)d_in[6];
    const float* ln1s = (const float*)d_in[7];
    const float* ln1b = (const float*)d_in[8];
    const float* W1   = (const float*)d_in[9];
    const float* b1   = (const float*)d_in[10];
    const float* W2   = (const float*)d_in[11];
    const float* b2   = (const float*)d_in[12];
    const float* ln2s = (const float*)d_in[13];
    const float* ln2b = (const float*)d_in[14];

    // ---- workspace layout (u16 elements), peak 142 MiB ----
    u16* ws   = (u16*)d_ws;
    u16* xb   = ws;                         // 8M  (x as fp16, 8192x1024)
    u16* WTq  = xb + (8u << 20);            // 1M
    u16* WTk  = WTq + (1u << 20);           // 1M
    u16* WTv  = WTk + (1u << 20);           // 1M
    u16* WTa  = WTv + (1u << 20);           // 2M
    u16* WTg  = WTa + (2u << 20);           // 1M
    u16* WTo  = WTg + (1u << 20);           // 1M
    u16* WT1  = WTo + (1u << 20);           // 4M
    u16* WT2  = WT1 + (4u << 20);           // 4M
    u16* qb   = WT2 + (4u << 20);           // 8M  (8192x1024)
    u16* kb   = qb + (8u << 20);            // 8M
    u16* vb   = kb + (8u << 20);            // 8M
    u16* ab   = vb + (8u << 20);            // 16M (8192x2048)
    u16* gb   = ab + (16u << 20);           // 8M
    // total = 71M u16 = 142 MiB

    // overlays (liveness audited against launch order):
    float4* sum4  = (float4*)WTq;             // 4 MiB over WTq+WTk (dead after projections)
    float2* carry = (float2*)WTv;             // 2 MiB over WTv (dead after projections)
    u16* yrb  = qb;   // scan3 writes y in-place over q
    u16* o1   = gb;   // Wo-GEMM out; g dead after scan3
    u16* ylnb = kb;   // LN1 out; k dead after scan3
    u16* hmat = vb;   // FFN hidden 8192x4096 = 32M u16, spans vb+ab+gb exactly
    u16* o2   = qb;   // FFN2 out; q/yr dead after Wo GEMM

    // x -> fp16
    cvt_f32_f16<<<dim3(8192), dim3(256), 0, stream>>>(x, xb);

    const dim3 tb(32, 32);
    transpose_f32_f16<<<dim3(32, 32), tb, 0, stream>>>(Wq, WTq, 1024, 1024);
    transpose_f32_f16<<<dim3(32, 32), tb, 0, stream>>>(Wk, WTk, 1024, 1024);
    transpose_f32_f16<<<dim3(32, 32), tb, 0, stream>>>(Wv, WTv, 1024, 1024);
    transpose_f32_f16<<<dim3(64, 32), tb, 0, stream>>>(Wa, WTa, 1024, 2048);
    transpose_f32_f16<<<dim3(32, 32), tb, 0, stream>>>(Wg, WTg, 1024, 1024);
    transpose_f32_f16<<<dim3(32, 32), tb, 0, stream>>>(Wo, WTo, 1024, 1024);
    transpose_f32_f16<<<dim3(128, 32), tb, 0, stream>>>(W1, WT1, 1024, 4096);
    transpose_f32_f16<<<dim3(32, 128), tb, 0, stream>>>(W2, WT2, 4096, 1024);

    const dim3 gblk(256);
    // projections (A = xb)
    gemm_bt<0><<<dim3(8, 64), gblk, 0, stream>>>(xb, WTq, qb, nullptr, Mtok, 1024, 1024);
    gemm_bt<0><<<dim3(8, 64), gblk, 0, stream>>>(xb, WTk, kb, nullptr, Mtok, 1024, 1024);
    gemm_bt<0><<<dim3(8, 64), gblk, 0, stream>>>(xb, WTv, vb, nullptr, Mtok, 1024, 1024);
    gemm_bt<0><<<dim3(16, 64), gblk, 0, stream>>>(xb, WTa, ab, nullptr, Mtok, 2048, 1024);
    gemm_bt<0><<<dim3(8, 64), gblk, 0, stream>>>(xb, WTg, gb, nullptr, Mtok, 1024, 1024);
    // gate-loop scan (sum4/carry clobber WTq/WTk/WTv — dead by now)
    scan1<<<dim3(NCH, Bb), 1024, 0, stream>>>(ab, kb, vb, sum4);
    scan2<<<dim3(8), 256, 0, stream>>>(sum4, carry);
    scan3<<<dim3(NCH, Bb), 1024, 0, stream>>>(ab, kb, vb, qb, gb, carry, yrb);
    // output proj + LN1 (residual = fp32 x)
    gemm_bt<0><<<dim3(8, 64), gblk, 0, stream>>>(yrb, WTo, o1, nullptr, Mtok, 1024, 1024);
    ln_kernel<1, 0><<<dim3(Mtok), dim3(256), 0, stream>>>(o1, x, ln1s, ln1b, ylnb);
    // FFN
    gemm_bt<1><<<dim3(32, 64), gblk, 0, stream>>>(ylnb, WT1, hmat, b1, Mtok, 4096, 1024);
    gemm_bt<2><<<dim3(8, 64), gblk, 0, stream>>>(hmat, WT2, o2, b2, Mtok, 1024, 4096);
    // LN2 -> fp32 output
    ln_kernel<0, 1><<<dim3(Mtok), dim3(256), 0, stream>>>(o2, ylnb, ln2s, ln2b, d_out);
}

// Round 6
// 607.099 us; speedup vs baseline: 1.0719x; 1.0719x over previous
//
#include <hip/hip_runtime.h>
#include <cstdint>

typedef unsigned short u16;
typedef unsigned int u32;

#define AS1 __attribute__((address_space(1)))
#define AS3 __attribute__((address_space(3)))

typedef _Float16 f16x8 __attribute__((ext_vector_type(8)));
typedef float f32x4 __attribute__((ext_vector_type(4)));

static constexpr int Bb = 2, Ss = 4096, Dd = 1024, Ff = 4096;
static constexpr int Mtok = Bb * Ss;          // 8192
static constexpr int NCH = 128;               // scan chunks per sequence
static constexpr int TCH = Ss / NCH;          // 32 steps per chunk
static constexpr int PW = 6144;               // fused projection width / pcat row stride

__device__ __forceinline__ float h2f(u16 u) {
    union { u16 u; _Float16 h; } w; w.u = u; return (float)w.h;
}
__device__ __forceinline__ u16 f2h(float f) {
    union { _Float16 h; u16 u; } w; w.h = (_Float16)f; return w.u;
}

// async global->LDS, 16 B per lane (m97 pattern; addrspacecast via C-cast)
__device__ __forceinline__ void gload_lds16(const u16* g, u16* l) {
    __builtin_amdgcn_global_load_lds((const AS1 u32*)g, (AS3 u32*)l, 16, 0, 0);
}

// ---------------- convert fp32 -> fp16, vectorized ----------------
__global__ __launch_bounds__(256) void cvt_f32_f16(const float* __restrict__ src,
                                                   u16* __restrict__ dst) {
    const long i = ((long)blockIdx.x * 256 + threadIdx.x) * 4;
    float4 f = *(const float4*)(src + i);
    ushort4 o;
    o.x = f2h(f.x); o.y = f2h(f.y); o.z = f2h(f.z); o.w = f2h(f.w);
    *(ushort4*)(dst + i) = o;
}

// ---------- transpose+convert: src fp32 [K,N] row-major -> dst fp16 [N,K] ----------
__global__ __launch_bounds__(1024) void transpose_f32_f16(const float* __restrict__ src,
                                                          u16* __restrict__ dst,
                                                          int K, int N) {
    __shared__ u16 t[32][33];
    const int tx = threadIdx.x, ty = threadIdx.y;
    const int n0 = blockIdx.x * 32, k0 = blockIdx.y * 32;
    t[ty][tx] = f2h(src[(long)(k0 + ty) * N + n0 + tx]);
    __syncthreads();
    dst[(long)(n0 + ty) * K + k0 + tx] = t[tx][ty];
}

// ------- GEMM: C[M,N] = A[M,K] @ B[K,N]; BT given [N,K] contiguous; A/C strided -------
// EPI: 0 = none, 1 = +bias, gelu(tanh), 2 = +bias   (bias fp32)
template <int EPI>
__global__ __launch_bounds__(256, 2) void gemm_bt(const u16* __restrict__ A,
                                                  const u16* __restrict__ BT,
                                                  u16* __restrict__ C,
                                                  const float* __restrict__ bias,
                                                  int M, int N, int K,
                                                  int lda, int ldc) {
    __shared__ __align__(16) u16 sA[128 * 32];
    __shared__ __align__(16) u16 sB[128 * 32];
    const int tid = threadIdx.x;
    const int tm = blockIdx.y * 128;
    const int tn = blockIdx.x * 128;
    const int w = tid >> 6;
    const int lane = tid & 63;
    const int wm = (w >> 1) * 64;
    const int wn = (w & 1) * 64;
    const int q = lane >> 4;
    const int r16 = lane & 15;

    f32x4 acc[4][4];
#pragma unroll
    for (int i = 0; i < 4; i++)
#pragma unroll
        for (int j = 0; j < 4; j++) acc[i][j] = (f32x4){0.f, 0.f, 0.f, 0.f};

    const int s0 = tid, s1 = 256 + tid;
    const int row0 = s0 >> 2, kc0 = (s0 & 3) * 8;
    const int row1 = s1 >> 2, kc1 = (s1 & 3) * 8;
    const u16* Ar0 = A + (long)(tm + row0) * lda + kc0;
    const u16* Ar1 = A + (long)(tm + row1) * lda + kc1;
    const u16* Br0 = BT + (long)(tn + row0) * K + kc0;
    const u16* Br1 = BT + (long)(tn + row1) * K + kc1;

    const int kiters = K >> 5;
    for (int kt = 0; kt < kiters; ++kt) {
        const int ko = kt * 32;
        gload_lds16(Ar0 + ko, sA + s0 * 8);
        gload_lds16(Ar1 + ko, sA + s1 * 8);
        gload_lds16(Br0 + ko, sB + s0 * 8);
        gload_lds16(Br1 + ko, sB + s1 * 8);
        __syncthreads();
        f16x8 af[4], bfr[4];
#pragma unroll
        for (int mi = 0; mi < 4; mi++)
            af[mi] = *(const f16x8*)(sA + (wm + mi * 16 + r16) * 32 + q * 8);
#pragma unroll
        for (int ni = 0; ni < 4; ni++)
            bfr[ni] = *(const f16x8*)(sB + (wn + ni * 16 + r16) * 32 + q * 8);
#pragma unroll
        for (int mi = 0; mi < 4; mi++)
#pragma unroll
            for (int ni = 0; ni < 4; ni++)
                acc[mi][ni] = __builtin_amdgcn_mfma_f32_16x16x32_f16(
                    af[mi], bfr[ni], acc[mi][ni], 0, 0, 0);
        __syncthreads();
    }

#pragma unroll
    for (int mi = 0; mi < 4; mi++) {
#pragma unroll
        for (int ni = 0; ni < 4; ni++) {
            const int gcol = tn + wn + ni * 16 + r16;
            float bv = 0.f;
            if (EPI) bv = bias[gcol];
#pragma unroll
            for (int j = 0; j < 4; j++) {
                const int grow = tm + wm + mi * 16 + q * 4 + j;
                float v = acc[mi][ni][j];
                if (EPI) v += bv;
                if (EPI == 1) {
                    float t = tanhf(0.7978845608028654f * (v + 0.044715f * v * v * v));
                    v = 0.5f * v * (1.0f + t);
                }
                C[(long)grow * ldc + gcol] = f2h(v);
            }
        }
    }
}

// ---------------- a_c transform helper ----------------
__device__ __forceinline__ void a_transform(float ar, float ai, float& cr, float& ci) {
    float m = sqrtf(ar * ar + ai * ai);
    float sg = 1.f / (1.f + __expf(-m));
    float sc = sg / fmaxf(m, 1e-30f);
    cr = ar * sc;
    ci = ai * sc;
}

// pcat column offsets: Q=0, K=1024, V=2048, AR=3072, AI=4096, G=5120; row stride PW.
// ---------------- scan phase 1: per-chunk reduce ----------------
__global__ __launch_bounds__(1024) void scan1(const u16* __restrict__ pcat,
                                              float4* __restrict__ sum4) {
    const int b = blockIdx.y, c = blockIdx.x, d = threadIdx.x;
    float Arp = 1.f, Aip = 0.f, Xr = 0.f, Xi = 0.f;
    const long rowbase = (long)b * Ss + (long)c * TCH;
#pragma unroll 4
    for (int s = 0; s < TCH; ++s) {
        const long ro = (rowbase + s) * PW;
        float ar = h2f(pcat[ro + 3072 + d]);
        float ai = h2f(pcat[ro + 4096 + d]);
        float kk = h2f(pcat[ro + 1024 + d]);
        float vv = h2f(pcat[ro + 2048 + d]);
        float cr, ci;
        a_transform(ar, ai, cr, ci);
        float kv = kk * vv;
        float nXr = cr * Xr - ci * Xi + kv;
        float nXi = cr * Xi + ci * Xr;
        Xr = nXr; Xi = nXi;
        float nAr = cr * Arp - ci * Aip;
        float nAi = cr * Aip + ci * Arp;
        Arp = nAr; Aip = nAi;
    }
    sum4[((long)b * NCH + c) * 1024 + d] = make_float4(Arp, Aip, Xr, Xi);
}

// ---------------- scan phase 2: sequential carry across chunks ----------------
__global__ __launch_bounds__(256) void scan2(const float4* __restrict__ sum4,
                                             float2* __restrict__ carry) {
    const int idx = blockIdx.x * 256 + threadIdx.x;  // 0..2047
    const int b = idx >> 10, d = idx & 1023;
    float hr = 0.f, hi = 0.f;
    for (int cb = 0; cb < NCH / 8; ++cb) {
        float4 t[8];
#pragma unroll
        for (int j = 0; j < 8; j++)
            t[j] = sum4[((long)b * NCH + cb * 8 + j) * 1024 + d];
#pragma unroll
        for (int j = 0; j < 8; j++) {
            carry[((long)b * NCH + cb * 8 + j) * 1024 + d] = make_float2(hr, hi);
            float nr = t[j].x * hr - t[j].y * hi + t[j].z;
            float ni = t[j].x * hi + t[j].y * hr + t[j].w;
            hr = nr; hi = ni;
        }
    }
}

// -------- scan phase 3: re-scan with carry, fused silu/q gating; y over Q in-place --------
__global__ __launch_bounds__(1024) void scan3(u16* pcat,
                                              const float2* __restrict__ carry) {
    const int b = blockIdx.y, c = blockIdx.x, d = threadIdx.x;
    float2 h0 = carry[((long)b * NCH + c) * 1024 + d];
    float hr = h0.x, hi = h0.y;
    const long rowbase = (long)b * Ss + (long)c * TCH;
#pragma unroll 4
    for (int s = 0; s < TCH; ++s) {
        const long ro = (rowbase + s) * PW;
        float ar = h2f(pcat[ro + 3072 + d]);
        float ai = h2f(pcat[ro + 4096 + d]);
        float kk = h2f(pcat[ro + 1024 + d]);
        float vv = h2f(pcat[ro + 2048 + d]);
        float cr, ci;
        a_transform(ar, ai, cr, ci);
        float kv = kk * vv;
        float nhr = cr * hr - ci * hi + kv;
        float nhi = cr * hi + ci * hr;
        hr = nhr; hi = nhi;
        float gg = h2f(pcat[ro + 5120 + d]);
        float si = gg / (1.f + __expf(-gg));
        float yv = h2f(pcat[ro + d]) * hr * si;
        pcat[ro + d] = f2h(yv);
    }
}

// ---------------- layernorm: out = LN(a + res) * scale + bias ----------------
// a: fp16 (stride sa). RESF32: res fp32 (stride sres). OUTF32: out fp32 (stride sout).
template <int RESF32, int OUTF32>
__global__ __launch_bounds__(256) void ln_kernel(const u16* __restrict__ a, int sa,
                                                 const void* __restrict__ bres, int sres,
                                                 const float* __restrict__ scale,
                                                 const float* __restrict__ bias,
                                                 void* __restrict__ out, int sout) {
    const int row = blockIdx.x;
    const int tid = threadIdx.x;
    const long abase = (long)row * sa;
    const long rbase = (long)row * sres;
    const long obase = (long)row * sout;
    float v[4];
#pragma unroll
    for (int j = 0; j < 4; j++) {
        int d = tid * 4 + j;
        float rb = RESF32 ? ((const float*)bres)[rbase + d]
                          : h2f(((const u16*)bres)[rbase + d]);
        v[j] = h2f(a[abase + d]) + rb;
    }
    float s = v[0] + v[1] + v[2] + v[3];
    float s2 = v[0] * v[0] + v[1] * v[1] + v[2] * v[2] + v[3] * v[3];
#pragma unroll
    for (int off = 32; off; off >>= 1) {
        s += __shfl_down(s, off);
        s2 += __shfl_down(s2, off);
    }
    __shared__ float red[8];
    const int w = tid >> 6, lane = tid & 63;
    if (lane == 0) { red[w] = s; red[4 + w] = s2; }
    __syncthreads();
    if (tid == 0) {
        float ts = red[0] + red[1] + red[2] + red[3];
        float ts2 = red[4] + red[5] + red[6] + red[7];
        float mu = ts * (1.f / 1024.f);
        float var = ts2 * (1.f / 1024.f) - mu * mu;
        red[0] = mu;
        red[1] = rsqrtf(var + 1e-6f);
    }
    __syncthreads();
    const float mu = red[0], rs = red[1];
#pragma unroll
    for (int j = 0; j < 4; j++) {
        int d = tid * 4 + j;
        float y = (v[j] - mu) * rs * scale[d] + bias[d];
        if (OUTF32) ((float*)out)[obase + d] = y;
        else        ((u16*)out)[obase + d] = f2h(y);
    }
}

extern "C" void kernel_launch(void* const* d_in, const int* in_sizes, int n_in,
                              void* d_out, int out_size, void* d_ws, size_t ws_size,
                              hipStream_t stream) {
    const float* x    = (const float*)d_in[0];
    const float* Wq   = (const float*)d_in[1];
    const float* Wk   = (const float*)d_in[2];
    const float* Wv   = (const float*)d_in[3];
    const float* Wa   = (const float*)d_in[4];
    const float* Wg   = (const float*)d_in[5];
    const float* Wo   = (const float*)d_in[6];
    const float* ln1s = (const float*)d_in[7];
    const float* ln1b = (const float*)d_in[8];
    const float* W1   = (const float*)d_in[9];
    const float* b1   = (const float*)d_in[10];
    const float* W2   = (const float*)d_in[11];
    const float* b2   = (const float*)d_in[12];
    const float* ln2s = (const float*)d_in[13];
    const float* ln2b = (const float*)d_in[14];

    // ---- workspace layout (u16 elements), 142 MiB total ----
    u16* ws    = (u16*)d_ws;
    u16* xb    = ws;                        // 8M   x as fp16
    u16* WTcat = xb + (8u << 20);           // 6M   [6144,1024] fused proj weights^T
    u16* WTo   = WTcat + (6u << 20);        // 1M
    u16* WT1   = WTo + (1u << 20);          // 4M
    u16* WT2   = WT1 + (4u << 20);          // 4M
    u16* pcat  = WT2 + (4u << 20);          // 48M  [8192,6144] everything lives here
    // total = 71M u16 = 142 MiB

    // scan scratch overlays WTcat (dead after the fused projection GEMM)
    float4* sum4  = (float4*)WTcat;               // 4 MiB
    float2* carry = (float2*)(WTcat + (2u << 20)); // 2 MiB @ +4 MiB

    // pcat column slices (row stride PW=6144):
    //   Q=+0  K=+1024  V=+2048  AR=+3072  AI=+4096  G=+5120
    // liveness ladder: scan3 writes y over Q; Wo-GEMM Q->K(o1); LN1 K->Q(yln);
    // FFN1 Q->cols[2048,6144)(hmat); FFN2 hmat->K(o2); LN2 (K,Q)->d_out.

    // x -> fp16
    cvt_f32_f16<<<dim3(8192), dim3(256), 0, stream>>>(x, xb);

    const dim3 tb(32, 32);
    transpose_f32_f16<<<dim3(32, 32), tb, 0, stream>>>(Wq, WTcat, 1024, 1024);
    transpose_f32_f16<<<dim3(32, 32), tb, 0, stream>>>(Wk, WTcat + (1u << 20), 1024, 1024);
    transpose_f32_f16<<<dim3(32, 32), tb, 0, stream>>>(Wv, WTcat + (2u << 20), 1024, 1024);
    transpose_f32_f16<<<dim3(64, 32), tb, 0, stream>>>(Wa, WTcat + (3u << 20), 1024, 2048);
    transpose_f32_f16<<<dim3(32, 32), tb, 0, stream>>>(Wg, WTcat + (5u << 20), 1024, 1024);
    transpose_f32_f16<<<dim3(32, 32), tb, 0, stream>>>(Wo, WTo, 1024, 1024);
    transpose_f32_f16<<<dim3(128, 32), tb, 0, stream>>>(W1, WT1, 1024, 4096);
    transpose_f32_f16<<<dim3(32, 128), tb, 0, stream>>>(W2, WT2, 4096, 1024);

    const dim3 gblk(256);
    // fused q|k|v|a|g projection: [8192,1024] @ [1024,6144] -> pcat
    gemm_bt<0><<<dim3(48, 64), gblk, 0, stream>>>(xb, WTcat, pcat, nullptr,
                                                  Mtok, PW, 1024, 1024, PW);
    // gate-loop scan
    scan1<<<dim3(NCH, Bb), 1024, 0, stream>>>(pcat, sum4);
    scan2<<<dim3(8), 256, 0, stream>>>(sum4, carry);
    scan3<<<dim3(NCH, Bb), 1024, 0, stream>>>(pcat, carry);
    // output proj: y(Q slice) @ Wo -> o1(K slice)
    gemm_bt<0><<<dim3(8, 64), gblk, 0, stream>>>(pcat, WTo, pcat + 1024, nullptr,
                                                 Mtok, 1024, 1024, PW, PW);
    // LN1: o1 + x -> yln(Q slice)
    ln_kernel<1, 0><<<dim3(Mtok), gblk, 0, stream>>>(pcat + 1024, PW, x, 1024,
                                                     ln1s, ln1b, pcat, PW);
    // FFN1: yln @ W1 + b1, gelu -> hmat(cols 2048..6144)
    gemm_bt<1><<<dim3(32, 64), gblk, 0, stream>>>(pcat, WT1, pcat + 2048, b1,
                                                  Mtok, Ff, 1024, PW, PW);
    // FFN2: hmat @ W2 + b2 -> o2(K slice)
    gemm_bt<2><<<dim3(8, 64), gblk, 0, stream>>>(pcat + 2048, WT2, pcat + 1024, b2,
                                                 Mtok, 1024, Ff, PW, PW);
    // LN2: o2 + yln -> fp32 d_out
    ln_kernel<0, 1><<<dim3(Mtok), gblk, 0, stream>>>(pcat + 1024, PW, pcat, PW,
                                                     ln2s, ln2b, d_out, 1024);
}